// Round 14
// baseline (1511.233 us; speedup 1.0000x reference)
//
#include <hip/hip_runtime.h>
#include <hip/hip_bf16.h>

#define HN 50000
#define HE 1600000
#define HP 100000
#define FIN 32
#define HH 128

// ---------------- workspace layout (4-byte units), total ~58.2 MB ----------------
#define OFF_CNT   0           // 50176 int (degree count, then reused as fill cursor)
#define OFF_DINV  50176       // 50176 f32
#define OFF_ROW   100352      // 50304 int (CSR row starts, HN+1)
#define OFF_ESRC  150656      // 1600000 int (CSR col = src node)
#define OFF_H     1750656     // 6.4M f32 (h; also serves as agg buffer)
#define OFF_Z     8150656     // 6.4M f32
#define OFF_BN    14550656    // 512 f32 (sum[128], sumsq[128], scale[128], shift[128])

__global__ __launch_bounds__(256) void k_deg_count(const int* __restrict__ ei,
                                                   int* __restrict__ cnt) {
    int e = blockIdx.x * 256 + threadIdx.x;
    if (e < HE) atomicAdd(&cnt[ei[HE + e]], 1);
}

__global__ __launch_bounds__(256) void k_dinv(const int* __restrict__ cnt,
                                              float* __restrict__ dinv) {
    int n = blockIdx.x * 256 + threadIdx.x;
    if (n < HN) dinv[n] = rsqrtf(1.0f + (float)cnt[n]);
}

// exclusive prefix sum of cnt -> rowstart; zero cnt (becomes fill cursor).
#define CHUNK 49  // 1024*49 = 50176 >= HN
__global__ __launch_bounds__(1024) void k_scan(int* __restrict__ cnt,
                                               int* __restrict__ rowstart) {
    __shared__ int sh[1024];
    int tid = threadIdx.x;
    int base = tid * CHUNK;
    int s = 0;
    for (int i = 0; i < CHUNK; ++i) {
        int idx = base + i;
        s += (idx < HN) ? cnt[idx] : 0;
    }
    sh[tid] = s;
    __syncthreads();
    for (int off = 1; off < 1024; off <<= 1) {
        int t = (tid >= off) ? sh[tid - off] : 0;
        __syncthreads();
        sh[tid] += t;
        __syncthreads();
    }
    int run = sh[tid] - s;  // exclusive prefix of this thread's chunk
    for (int i = 0; i < CHUNK; ++i) {
        int idx = base + i;
        if (idx < HN) {
            int cv = cnt[idx];
            rowstart[idx] = run;
            run += cv;
            cnt[idx] = 0;  // reset: becomes the fill cursor
        }
    }
    if (tid == 1023) rowstart[HN] = run;  // == HE
}

__global__ __launch_bounds__(256) void k_fill(const int* __restrict__ ei,
                                              const int* __restrict__ rowstart,
                                              int* __restrict__ cursor,
                                              int* __restrict__ esrc) {
    int e = blockIdx.x * 256 + threadIdx.x;
    if (e < HE) {
        int s = ei[e];
        int d = ei[HE + e];
        int pos = rowstart[d] + atomicAdd(&cursor[d], 1);
        esrc[pos] = s;
    }
}

// h = relu(x @ W_emb + b_emb)   x:[N,32] f32, W:[32,128] f32 -> h f32
__global__ __launch_bounds__(128) void k_embed(const float* __restrict__ x,
                                               const float* __restrict__ W,
                                               const float* __restrict__ b,
                                               float* __restrict__ h) {
    __shared__ float xs[32 * FIN];
    int n0 = blockIdx.x * 32;
    int tid = threadIdx.x;
    for (int i = tid; i < 32 * FIN; i += 128) {
        int n = n0 + (i >> 5);
        xs[i] = (n < HN) ? x[n0 * FIN + i] : 0.0f;
    }
    __syncthreads();
    int j = tid;
    float bj = b[j];
    float acc[32];
#pragma unroll
    for (int p = 0; p < 32; ++p) acc[p] = bj;
    for (int k4 = 0; k4 < FIN; k4 += 4) {
        float w0 = W[(k4 + 0) * HH + j];
        float w1 = W[(k4 + 1) * HH + j];
        float w2 = W[(k4 + 2) * HH + j];
        float w3 = W[(k4 + 3) * HH + j];
#pragma unroll
        for (int p = 0; p < 32; ++p) {
            float4 v = *(const float4*)&xs[p * FIN + k4];
            acc[p] += v.x * w0 + v.y * w1 + v.z * w2 + v.w * w3;
        }
    }
    for (int p = 0; p < 32; ++p) {
        int n = n0 + p;
        if (n < HN) h[n * HH + j] = fmaxf(acc[p], 0.0f);
    }
}

// z = h @ W   (h f32 [N,128], W f32 [128,128])
__global__ __launch_bounds__(128) void k_gemm128(const float* __restrict__ hin,
                                                 const float* __restrict__ W,
                                                 float* __restrict__ z) {
    __shared__ float hs[32 * HH];
    int n0 = blockIdx.x * 32;
    int tid = threadIdx.x;
    for (int i = tid; i < 32 * HH; i += 128) {
        int n = n0 + (i >> 7);
        hs[i] = (n < HN) ? hin[n0 * HH + i] : 0.0f;
    }
    __syncthreads();
    float acc[32];
#pragma unroll
    for (int p = 0; p < 32; ++p) acc[p] = 0.0f;
    for (int k4 = 0; k4 < HH; k4 += 4) {
        float w0 = W[(k4 + 0) * HH + tid];
        float w1 = W[(k4 + 1) * HH + tid];
        float w2 = W[(k4 + 2) * HH + tid];
        float w3 = W[(k4 + 3) * HH + tid];
#pragma unroll
        for (int p = 0; p < 32; ++p) {
            float4 v = *(const float4*)&hs[p * HH + k4];
            acc[p] += v.x * w0 + v.y * w1 + v.z * w2 + v.w * w3;
        }
    }
    for (int p = 0; p < 32; ++p) {
        int n = n0 + p;
        if (n < HN) z[n * HH + tid] = acc[p];
    }
}

// pull-mode aggregation: one wave per dst row; lane holds 2 channels (float2).
// agg[d] = dinv[d] * sum_e dinv[src_e]*z[src_e] + dinv[d]^2 * z[d] + bias
// Writes into the h buffer (h's old value already consumed by k_gemm128).
__global__ __launch_bounds__(256) void k_pull(const int* __restrict__ rowstart,
                                              const int* __restrict__ esrc,
                                              const float* __restrict__ z,
                                              const float* __restrict__ dinv,
                                              const float* __restrict__ b,
                                              float* __restrict__ agg) {
    int wid = (blockIdx.x * 256 + threadIdx.x) >> 6;  // dst row
    int lane = threadIdx.x & 63;
    if (wid >= HN) return;
    int beg = rowstart[wid], end = rowstart[wid + 1];
    const float2* z2 = (const float2*)z;
    float2 acc = make_float2(0.f, 0.f);
    for (int i = beg; i < end; ++i) {
        int s = esrc[i];        // wave-uniform
        float w = dinv[s];      // wave-uniform, L2-resident
        float2 v = z2[s * 64 + lane];
        acc.x = fmaf(w, v.x, acc.x);
        acc.y = fmaf(w, v.y, acc.y);
    }
    float dvd = dinv[wid];
    float ns = dvd * dvd;
    float2 vz = z2[wid * 64 + lane];
    acc.x = fmaf(dvd, acc.x, fmaf(ns, vz.x, b[2 * lane]));
    acc.y = fmaf(dvd, acc.y, fmaf(ns, vz.y, b[2 * lane + 1]));
    ((float2*)agg)[wid * 64 + lane] = acc;
}

// per-channel sum/sumsq of buf
__global__ __launch_bounds__(256) void k_bnstats(const float* __restrict__ buf,
                                                 float* __restrict__ bnsum) {
    int tid = threadIdx.x;
    int c = tid & 127;
    float s1 = 0.f, s2 = 0.f;
    long long total = (long long)HN * HH;
    long long stride = (long long)gridDim.x * 256;
    for (long long i = (long long)blockIdx.x * 256 + tid; i < total; i += stride) {
        float v = buf[i];
        s1 += v;
        s2 += v * v;
    }
    __shared__ float sh1[256], sh2[256];
    sh1[tid] = s1;
    sh2[tid] = s2;
    __syncthreads();
    if (tid < 128) {
        atomicAdd(&bnsum[c], sh1[tid] + sh1[tid + 128]);
        atomicAdd(&bnsum[128 + c], sh2[tid] + sh2[tid + 128]);
    }
}

__global__ void k_bnfin(const float* __restrict__ bnsum,
                        const float* __restrict__ gamma,
                        const float* __restrict__ beta,
                        float* __restrict__ ss) {
    int c = threadIdx.x;
    float mu = bnsum[c] * (1.0f / HN);
    float var = bnsum[128 + c] * (1.0f / HN) - mu * mu;
    float sc = gamma[c] * rsqrtf(var + 1e-5f);
    ss[c] = sc;
    ss[128 + c] = beta[c] - mu * sc;
}

// in-place BN apply (+ optional relu)
__global__ __launch_bounds__(256) void k_bnapply(float* __restrict__ buf,
                                                 const float* __restrict__ ss,
                                                 int relu) {
    long long total = (long long)HN * HH;
    long long stride = (long long)gridDim.x * 256;
    for (long long i = (long long)blockIdx.x * 256 + threadIdx.x; i < total; i += stride) {
        int c = (int)(i & 127);
        float v = ss[c] * buf[i] + ss[128 + c];
        if (relu) v = fmaxf(v, 0.f);
        buf[i] = v;
    }
}

// fused pairwise MLP: 32 pairs per block, 128 threads; f32 output
#define IL 264
__global__ __launch_bounds__(128) void k_mlp(const float* __restrict__ h,
                                             const int* __restrict__ srcn,
                                             const int* __restrict__ tgtn,
                                             const float* __restrict__ tf,
                                             const float* __restrict__ W1,
                                             const float* __restrict__ b1,
                                             const float* __restrict__ W2,
                                             const float* __restrict__ b2,
                                             const float* __restrict__ W3,
                                             const float* __restrict__ b3,
                                             float* __restrict__ out) {
    __shared__ float inb[32 * IL];
    __shared__ float y1s[32 * 128];
    __shared__ float y2s[32 * 64];
    __shared__ int sns[32], tns[32];
    int tid = threadIdx.x;
    int p0 = blockIdx.x * 32;
    if (tid < 32) {
        int pp = p0 + tid;
        sns[tid] = (pp < HP) ? srcn[pp] : 0;
        tns[tid] = (pp < HP) ? tgtn[pp] : 0;
    }
    __syncthreads();
    for (int i = tid; i < 32 * 128; i += 128) {
        int p = i >> 7, k = i & 127;
        inb[p * IL + k] = h[sns[p] * HH + k];
        inb[p * IL + 128 + k] = h[tns[p] * HH + k];
    }
    if (tid < 64) {
        int p = tid >> 1, t = tid & 1;
        int pp = p0 + p;
        inb[p * IL + 256 + t] = (pp < HP) ? tf[pp * 2 + t] : 0.f;
    }
    __syncthreads();
    // y1 = relu(flow_in @ W1 + b1)
    {
        int j = tid;
        float bj = b1[j];
        float acc[32];
#pragma unroll
        for (int p = 0; p < 32; ++p) acc[p] = bj;
        for (int k4 = 0; k4 < 256; k4 += 4) {
            float w0 = W1[(k4 + 0) * HH + j];
            float w1 = W1[(k4 + 1) * HH + j];
            float w2 = W1[(k4 + 2) * HH + j];
            float w3 = W1[(k4 + 3) * HH + j];
#pragma unroll
            for (int p = 0; p < 32; ++p) {
                float4 v = *(const float4*)&inb[p * IL + k4];
                acc[p] += v.x * w0 + v.y * w1 + v.z * w2 + v.w * w3;
            }
        }
        {
            float w0 = W1[256 * HH + j];
            float w1 = W1[257 * HH + j];
#pragma unroll
            for (int p = 0; p < 32; ++p)
                acc[p] += inb[p * IL + 256] * w0 + inb[p * IL + 257] * w1;
        }
        for (int p = 0; p < 32; ++p) y1s[p * 128 + j] = fmaxf(acc[p], 0.f);
    }
    __syncthreads();
    // y2 = relu(y1 @ W2 + b2)
    {
        int j = tid & 63, pg = tid >> 6;
        float bj = b2[j];
        float acc[16];
#pragma unroll
        for (int q = 0; q < 16; ++q) acc[q] = bj;
        for (int k4 = 0; k4 < 128; k4 += 4) {
            float w0 = W2[(k4 + 0) * 64 + j];
            float w1 = W2[(k4 + 1) * 64 + j];
            float w2 = W2[(k4 + 2) * 64 + j];
            float w3 = W2[(k4 + 3) * 64 + j];
#pragma unroll
            for (int q = 0; q < 16; ++q) {
                float4 v = *(const float4*)&y1s[(pg * 16 + q) * 128 + k4];
                acc[q] += v.x * w0 + v.y * w1 + v.z * w2 + v.w * w3;
            }
        }
        for (int q = 0; q < 16; ++q) y2s[(pg * 16 + q) * 64 + j] = fmaxf(acc[q], 0.f);
    }
    __syncthreads();
    // y3 = y2 @ W3 + b3
    if (tid < 32) {
        int p = tid;
        float acc = b3[0];
        for (int k = 0; k < 64; ++k) acc += y2s[p * 64 + k] * W3[k];
        int pp = p0 + p;
        if (pp < HP) out[pp] = acc;
    }
}

extern "C" void kernel_launch(void* const* d_in, const int* in_sizes, int n_in,
                              void* d_out, int out_size, void* d_ws, size_t ws_size,
                              hipStream_t stream) {
    const float* x      = (const float*)d_in[0];
    const int*   ei     = (const int*)d_in[1];
    const int*   srcn   = (const int*)d_in[2];
    const int*   tgtn   = (const int*)d_in[3];
    const float* tf     = (const float*)d_in[4];
    const float* W_emb  = (const float*)d_in[5];
    const float* b_emb  = (const float*)d_in[6];
    const float* Ws     = (const float*)d_in[7];
    const float* bs     = (const float*)d_in[8];
    const float* gammas = (const float*)d_in[9];
    const float* betas  = (const float*)d_in[10];
    const float* W1     = (const float*)d_in[11];
    const float* b1     = (const float*)d_in[12];
    const float* W2     = (const float*)d_in[13];
    const float* b2     = (const float*)d_in[14];
    const float* W3     = (const float*)d_in[15];
    const float* b3     = (const float*)d_in[16];
    float* ws   = (float*)d_ws;
    int*   cnt  = (int*)(ws + OFF_CNT);
    float* dinv = ws + OFF_DINV;
    int*   row  = (int*)(ws + OFF_ROW);
    int*   esrc = (int*)(ws + OFF_ESRC);
    float* h    = ws + OFF_H;     // doubles as agg
    float* z    = ws + OFF_Z;
    float* bn   = ws + OFF_BN;
    float* out  = (float*)d_out;

    hipMemsetAsync(cnt, 0, HN * sizeof(int), stream);
    k_deg_count<<<(HE + 255) / 256, 256, 0, stream>>>(ei, cnt);
    k_dinv<<<(HN + 255) / 256, 256, 0, stream>>>(cnt, dinv);
    k_scan<<<1, 1024, 0, stream>>>(cnt, row);
    k_fill<<<(HE + 255) / 256, 256, 0, stream>>>(ei, row, cnt, esrc);
    k_embed<<<(HN + 31) / 32, 128, 0, stream>>>(x, W_emb, b_emb, h);
    for (int l = 0; l < 3; ++l) {
        k_gemm128<<<(HN + 31) / 32, 128, 0, stream>>>(h, Ws + l * HH * HH, z);
        hipMemsetAsync(bn, 0, 256 * sizeof(float), stream);
        k_pull<<<(HN * 64 + 255) / 256, 256, 0, stream>>>(row, esrc, z, dinv,
                                                          bs + l * HH, h);
        k_bnstats<<<1024, 256, 0, stream>>>(h, bn);
        k_bnfin<<<1, 128, 0, stream>>>(bn, gammas + l * HH, betas + l * HH, bn + 256);
        k_bnapply<<<1024, 256, 0, stream>>>(h, bn + 256, (l < 2) ? 1 : 0);
    }
    k_mlp<<<HP / 32, 128, 0, stream>>>(h, srcn, tgtn, tf, W1, b1, W2, b2, W3, b3, out);
}

// Round 18
// 1373.413 us; speedup vs baseline: 1.1003x; 1.1003x over previous
//
#include <hip/hip_runtime.h>
#include <hip/hip_bf16.h>

typedef __hip_bfloat16 bf16;

#define HN 50000
#define HE 1600000
#define HP 100000
#define FIN 32
#define HH 128

// ---------------- workspace layout (4-byte units) ----------------
#define OFF_CNT   0           // 50176 int (degree count, then reused as fill cursor)
#define OFF_DINV  50176       // 50176 f32
#define OFF_ROW   100352      // 50304 int (CSR row starts, HN+1)
#define OFF_ESRC  150656      // 1600000 int (CSR col = src node)
#define OFF_H     1750656     // 6.4M f32 (h; also serves as agg buffer)
#define OFF_Z     8150656     // z as bf16: 50000*128*2B = 12.8MB (3.2M slots)
#define OFF_BN    14550656    // 512 f32 (sum[128], sumsq[128], scale[128], shift[128])

__global__ __launch_bounds__(256) void k_deg_count(const int* __restrict__ ei,
                                                   int* __restrict__ cnt) {
    int e = blockIdx.x * 256 + threadIdx.x;
    if (e < HE) atomicAdd(&cnt[ei[HE + e]], 1);
}

__global__ __launch_bounds__(256) void k_dinv(const int* __restrict__ cnt,
                                              float* __restrict__ dinv) {
    int n = blockIdx.x * 256 + threadIdx.x;
    if (n < HN) dinv[n] = rsqrtf(1.0f + (float)cnt[n]);
}

// exclusive prefix sum of cnt -> rowstart; zero cnt (becomes fill cursor).
#define CHUNK 49  // 1024*49 = 50176 >= HN
__global__ __launch_bounds__(1024) void k_scan(int* __restrict__ cnt,
                                               int* __restrict__ rowstart) {
    __shared__ int sh[1024];
    int tid = threadIdx.x;
    int base = tid * CHUNK;
    int s = 0;
    for (int i = 0; i < CHUNK; ++i) {
        int idx = base + i;
        s += (idx < HN) ? cnt[idx] : 0;
    }
    sh[tid] = s;
    __syncthreads();
    for (int off = 1; off < 1024; off <<= 1) {
        int t = (tid >= off) ? sh[tid - off] : 0;
        __syncthreads();
        sh[tid] += t;
        __syncthreads();
    }
    int run = sh[tid] - s;  // exclusive prefix of this thread's chunk
    for (int i = 0; i < CHUNK; ++i) {
        int idx = base + i;
        if (idx < HN) {
            int cv = cnt[idx];
            rowstart[idx] = run;
            run += cv;
            cnt[idx] = 0;  // reset: becomes the fill cursor
        }
    }
    if (tid == 1023) rowstart[HN] = run;  // == HE
}

__global__ __launch_bounds__(256) void k_fill(const int* __restrict__ ei,
                                              const int* __restrict__ rowstart,
                                              int* __restrict__ cursor,
                                              int* __restrict__ esrc) {
    int e = blockIdx.x * 256 + threadIdx.x;
    if (e < HE) {
        int s = ei[e];
        int d = ei[HE + e];
        int pos = rowstart[d] + atomicAdd(&cursor[d], 1);
        esrc[pos] = s;
    }
}

// h = relu(x @ W_emb + b_emb)   x:[N,32] f32, W:[32,128] f32 -> h f32
__global__ __launch_bounds__(128) void k_embed(const float* __restrict__ x,
                                               const float* __restrict__ W,
                                               const float* __restrict__ b,
                                               float* __restrict__ h) {
    __shared__ float xs[32 * FIN];
    int n0 = blockIdx.x * 32;
    int tid = threadIdx.x;
    for (int i = tid; i < 32 * FIN; i += 128) {
        int n = n0 + (i >> 5);
        xs[i] = (n < HN) ? x[n0 * FIN + i] : 0.0f;
    }
    __syncthreads();
    int j = tid;
    float bj = b[j];
    float acc[32];
#pragma unroll
    for (int p = 0; p < 32; ++p) acc[p] = bj;
    for (int k4 = 0; k4 < FIN; k4 += 4) {
        float w0 = W[(k4 + 0) * HH + j];
        float w1 = W[(k4 + 1) * HH + j];
        float w2 = W[(k4 + 2) * HH + j];
        float w3 = W[(k4 + 3) * HH + j];
#pragma unroll
        for (int p = 0; p < 32; ++p) {
            float4 v = *(const float4*)&xs[p * FIN + k4];
            acc[p] += v.x * w0 + v.y * w1 + v.z * w2 + v.w * w3;
        }
    }
    for (int p = 0; p < 32; ++p) {
        int n = n0 + p;
        if (n < HN) h[n * HH + j] = fmaxf(acc[p], 0.0f);
    }
}

// z = h @ W   (h f32 [N,128], W f32 [128,128]) -> z bf16
__global__ __launch_bounds__(128) void k_gemm128(const float* __restrict__ hin,
                                                 const float* __restrict__ W,
                                                 bf16* __restrict__ z) {
    __shared__ float hs[32 * HH];
    int n0 = blockIdx.x * 32;
    int tid = threadIdx.x;
    for (int i = tid; i < 32 * HH; i += 128) {
        int n = n0 + (i >> 7);
        hs[i] = (n < HN) ? hin[n0 * HH + i] : 0.0f;
    }
    __syncthreads();
    float acc[32];
#pragma unroll
    for (int p = 0; p < 32; ++p) acc[p] = 0.0f;
    for (int k4 = 0; k4 < HH; k4 += 4) {
        float w0 = W[(k4 + 0) * HH + tid];
        float w1 = W[(k4 + 1) * HH + tid];
        float w2 = W[(k4 + 2) * HH + tid];
        float w3 = W[(k4 + 3) * HH + tid];
#pragma unroll
        for (int p = 0; p < 32; ++p) {
            float4 v = *(const float4*)&hs[p * HH + k4];
            acc[p] += v.x * w0 + v.y * w1 + v.z * w2 + v.w * w3;
        }
    }
    for (int p = 0; p < 32; ++p) {
        int n = n0 + p;
        if (n < HN) z[n * HH + tid] = __float2bfloat16(acc[p]);
    }
}

// pull-mode aggregation: one wave per dst row; lane holds 2 bf16 channels (1 uint).
// agg[d] = dinv[d] * sum_e dinv[src_e]*z[src_e] + dinv[d]^2 * z[d] + bias
__global__ __launch_bounds__(256) void k_pull(const int* __restrict__ rowstart,
                                              const int* __restrict__ esrc,
                                              const unsigned int* __restrict__ zb,
                                              const float* __restrict__ dinv,
                                              const float* __restrict__ b,
                                              float* __restrict__ agg) {
    int wid = (blockIdx.x * 256 + threadIdx.x) >> 6;  // dst row
    int lane = threadIdx.x & 63;
    if (wid >= HN) return;
    int beg = rowstart[wid], end = rowstart[wid + 1];
    float2 acc = make_float2(0.f, 0.f);
    for (int i = beg; i < end; ++i) {
        int s = esrc[i];        // wave-uniform
        float w = dinv[s];      // wave-uniform, L2-resident
        unsigned int v = zb[s * 64 + lane];   // 2 bf16 channels, 4B/lane gather
        float lo = __uint_as_float(v << 16);
        float hi = __uint_as_float(v & 0xffff0000u);
        acc.x = fmaf(w, lo, acc.x);
        acc.y = fmaf(w, hi, acc.y);
    }
    float dvd = dinv[wid];
    float ns = dvd * dvd;
    unsigned int vs = zb[wid * 64 + lane];
    float slo = __uint_as_float(vs << 16);
    float shi = __uint_as_float(vs & 0xffff0000u);
    acc.x = fmaf(dvd, acc.x, fmaf(ns, slo, b[2 * lane]));
    acc.y = fmaf(dvd, acc.y, fmaf(ns, shi, b[2 * lane + 1]));
    ((float2*)agg)[wid * 64 + lane] = acc;
}

// per-channel sum/sumsq of buf
__global__ __launch_bounds__(256) void k_bnstats(const float* __restrict__ buf,
                                                 float* __restrict__ bnsum) {
    int tid = threadIdx.x;
    int c = tid & 127;
    float s1 = 0.f, s2 = 0.f;
    long long total = (long long)HN * HH;
    long long stride = (long long)gridDim.x * 256;
    for (long long i = (long long)blockIdx.x * 256 + tid; i < total; i += stride) {
        float v = buf[i];
        s1 += v;
        s2 += v * v;
    }
    __shared__ float sh1[256], sh2[256];
    sh1[tid] = s1;
    sh2[tid] = s2;
    __syncthreads();
    if (tid < 128) {
        atomicAdd(&bnsum[c], sh1[tid] + sh1[tid + 128]);
        atomicAdd(&bnsum[128 + c], sh2[tid] + sh2[tid + 128]);
    }
}

__global__ void k_bnfin(const float* __restrict__ bnsum,
                        const float* __restrict__ gamma,
                        const float* __restrict__ beta,
                        float* __restrict__ ss) {
    int c = threadIdx.x;
    float mu = bnsum[c] * (1.0f / HN);
    float var = bnsum[128 + c] * (1.0f / HN) - mu * mu;
    float sc = gamma[c] * rsqrtf(var + 1e-5f);
    ss[c] = sc;
    ss[128 + c] = beta[c] - mu * sc;
}

// in-place BN apply (+ optional relu)
__global__ __launch_bounds__(256) void k_bnapply(float* __restrict__ buf,
                                                 const float* __restrict__ ss,
                                                 int relu) {
    long long total = (long long)HN * HH;
    long long stride = (long long)gridDim.x * 256;
    for (long long i = (long long)blockIdx.x * 256 + threadIdx.x; i < total; i += stride) {
        int c = (int)(i & 127);
        float v = ss[c] * buf[i] + ss[128 + c];
        if (relu) v = fmaxf(v, 0.f);
        buf[i] = v;
    }
}

// fused pairwise MLP: 16 pairs per block, 128 threads; f32 output
// LDS ~29.4 KB -> 5 blocks/CU (~27% occupancy, was 10%)
#define PB 16
#define IL 264   // inb row stride (floats), keeps float4 alignment
#define Y2L 65   // y2s padded stride: kills stride-64 bank conflict in y3
__global__ __launch_bounds__(128) void k_mlp(const float* __restrict__ h,
                                             const int* __restrict__ srcn,
                                             const int* __restrict__ tgtn,
                                             const float* __restrict__ tf,
                                             const float* __restrict__ W1,
                                             const float* __restrict__ b1,
                                             const float* __restrict__ W2,
                                             const float* __restrict__ b2,
                                             const float* __restrict__ W3,
                                             const float* __restrict__ b3,
                                             float* __restrict__ out) {
    __shared__ float inb[PB * IL];
    __shared__ float y1s[PB * 128];
    __shared__ float y2s[PB * Y2L];
    __shared__ int sns[PB], tns[PB];
    int tid = threadIdx.x;
    int p0 = blockIdx.x * PB;
    if (tid < PB) {
        int pp = p0 + tid;
        sns[tid] = (pp < HP) ? srcn[pp] : 0;
        tns[tid] = (pp < HP) ? tgtn[pp] : 0;
    }
    __syncthreads();
    for (int i = tid; i < PB * 128; i += 128) {
        int p = i >> 7, k = i & 127;
        inb[p * IL + k] = h[sns[p] * HH + k];
        inb[p * IL + 128 + k] = h[tns[p] * HH + k];
    }
    if (tid < 2 * PB) {
        int p = tid >> 1, t = tid & 1;
        int pp = p0 + p;
        inb[p * IL + 256 + t] = (pp < HP) ? tf[pp * 2 + t] : 0.f;
    }
    __syncthreads();
    // y1 = relu(flow_in @ W1 + b1): thread j accumulates PB pairs
    {
        int j = tid;
        float bj = b1[j];
        float acc[PB];
#pragma unroll
        for (int p = 0; p < PB; ++p) acc[p] = bj;
        for (int k4 = 0; k4 < 256; k4 += 4) {
            float w0 = W1[(k4 + 0) * HH + j];
            float w1 = W1[(k4 + 1) * HH + j];
            float w2 = W1[(k4 + 2) * HH + j];
            float w3 = W1[(k4 + 3) * HH + j];
#pragma unroll
            for (int p = 0; p < PB; ++p) {
                float4 v = *(const float4*)&inb[p * IL + k4];
                acc[p] += v.x * w0 + v.y * w1 + v.z * w2 + v.w * w3;
            }
        }
        {
            float w0 = W1[256 * HH + j];
            float w1 = W1[257 * HH + j];
#pragma unroll
            for (int p = 0; p < PB; ++p)
                acc[p] += inb[p * IL + 256] * w0 + inb[p * IL + 257] * w1;
        }
        for (int p = 0; p < PB; ++p) y1s[p * 128 + j] = fmaxf(acc[p], 0.f);
    }
    __syncthreads();
    // y2 = relu(y1 @ W2 + b2): 64 out cols; tid&63 = col, tid>>6 picks PB/2 pairs
    {
        int j = tid & 63, pg = tid >> 6;
        float bj = b2[j];
        float acc[PB / 2];
#pragma unroll
        for (int q = 0; q < PB / 2; ++q) acc[q] = bj;
        for (int k4 = 0; k4 < 128; k4 += 4) {
            float w0 = W2[(k4 + 0) * 64 + j];
            float w1 = W2[(k4 + 1) * 64 + j];
            float w2 = W2[(k4 + 2) * 64 + j];
            float w3 = W2[(k4 + 3) * 64 + j];
#pragma unroll
            for (int q = 0; q < PB / 2; ++q) {
                float4 v = *(const float4*)&y1s[(pg * (PB / 2) + q) * 128 + k4];
                acc[q] += v.x * w0 + v.y * w1 + v.z * w2 + v.w * w3;
            }
        }
        for (int q = 0; q < PB / 2; ++q)
            y2s[(pg * (PB / 2) + q) * Y2L + j] = fmaxf(acc[q], 0.f);
    }
    __syncthreads();
    // y3 = y2 @ W3 + b3: one thread per pair (padded stride -> conflict-free)
    if (tid < PB) {
        int p = tid;
        float acc = b3[0];
        for (int k = 0; k < 64; ++k) acc += y2s[p * Y2L + k] * W3[k];
        int pp = p0 + p;
        if (pp < HP) out[pp] = acc;
    }
}

extern "C" void kernel_launch(void* const* d_in, const int* in_sizes, int n_in,
                              void* d_out, int out_size, void* d_ws, size_t ws_size,
                              hipStream_t stream) {
    const float* x      = (const float*)d_in[0];
    const int*   ei     = (const int*)d_in[1];
    const int*   srcn   = (const int*)d_in[2];
    const int*   tgtn   = (const int*)d_in[3];
    const float* tf     = (const float*)d_in[4];
    const float* W_emb  = (const float*)d_in[5];
    const float* b_emb  = (const float*)d_in[6];
    const float* Ws     = (const float*)d_in[7];
    const float* bs     = (const float*)d_in[8];
    const float* gammas = (const float*)d_in[9];
    const float* betas  = (const float*)d_in[10];
    const float* W1     = (const float*)d_in[11];
    const float* b1     = (const float*)d_in[12];
    const float* W2     = (const float*)d_in[13];
    const float* b2     = (const float*)d_in[14];
    const float* W3     = (const float*)d_in[15];
    const float* b3     = (const float*)d_in[16];
    float* ws   = (float*)d_ws;
    int*   cnt  = (int*)(ws + OFF_CNT);
    float* dinv = ws + OFF_DINV;
    int*   row  = (int*)(ws + OFF_ROW);
    int*   esrc = (int*)(ws + OFF_ESRC);
    float* h    = ws + OFF_H;     // doubles as agg
    bf16*  zb   = (bf16*)(ws + OFF_Z);
    float* bn   = ws + OFF_BN;
    float* out  = (float*)d_out;

    hipMemsetAsync(cnt, 0, HN * sizeof(int), stream);
    k_deg_count<<<(HE + 255) / 256, 256, 0, stream>>>(ei, cnt);
    k_dinv<<<(HN + 255) / 256, 256, 0, stream>>>(cnt, dinv);
    k_scan<<<1, 1024, 0, stream>>>(cnt, row);
    k_fill<<<(HE + 255) / 256, 256, 0, stream>>>(ei, row, cnt, esrc);
    k_embed<<<(HN + 31) / 32, 128, 0, stream>>>(x, W_emb, b_emb, h);
    for (int l = 0; l < 3; ++l) {
        k_gemm128<<<(HN + 31) / 32, 128, 0, stream>>>(h, Ws + l * HH * HH, zb);
        hipMemsetAsync(bn, 0, 256 * sizeof(float), stream);
        k_pull<<<(HN * 64 + 255) / 256, 256, 0, stream>>>(row, esrc,
                                                          (const unsigned int*)zb,
                                                          dinv, bs + l * HH, h);
        k_bnstats<<<1024, 256, 0, stream>>>(h, bn);
        k_bnfin<<<1, 128, 0, stream>>>(bn, gammas + l * HH, betas + l * HH, bn + 256);
        k_bnapply<<<1024, 256, 0, stream>>>(h, bn + 256, (l < 2) ? 1 : 0);
    }
    k_mlp<<<HP / PB, 128, 0, stream>>>(h, srcn, tgtn, tf, W1, b1, W2, b2, W3, b3, out);
}